// Round 3
// baseline (686.020 us; speedup 1.0000x reference)
//
#include <hip/hip_runtime.h>
#include <cstdint>

// LoRA mixture kernel for B=8, S=4096, D=2048, R=4, N=32.
// Math: for batch b0, out = relu(0.25 * sum_{j=4b0}^{4b0+3} (x @ B_j) @ A_j).
//
// Round-2 fixes (from rocprof: lora_h latency-bound, 658 GB/s, 10.8% occ):
//  1. b0 derived from blockIdx (wave-uniform) so Bpack reads become s_load
//     on the scalar pipe instead of 16 vector loads per d4-step clogging vmcnt.
//  2. SEGS 2->8 (ws permitting): 4096 one-wave blocks = 16 waves/CU.
//  3. unroll 8: each unrolled body consumes a lane's full 128B line.

namespace {

constexpr int D = 2048;
constexpr int R = 4;
constexpr int B = 8;
constexpr int S = 4096;
constexpr int NROWS = B * S;        // 32768 total rows
constexpr int T = 16;               // 4 adapters x rank 4

// ws layout (floats): [0, B*D*T) Bpack (2 MB); then SEGS*NROWS*T Hpart.

__global__ __launch_bounds__(256) void pack_b_kernel(const float* __restrict__ ab,
                                                     float* __restrict__ bpack) {
  int idx = blockIdx.x * 256 + threadIdx.x;      // over B*D*T = 262144
  if (idx >= B * D * T) return;
  int t  = idx & 15;
  int d  = (idx >> 4) & (D - 1);
  int b0 = idx >> 15;
  int j = 4 * b0 + (t >> 2);                     // adapter id
  int r = t & 3;                                 // rank index
  bpack[idx] = ab[((size_t)j * D + d) * R + r];
}

// One wave per block; lane = row within a 64-row block; each lane reduces its
// own row over a (D/SEGS)-wide d-segment. b0/seg are SGPR-derived so Bpack
// reads are wave-uniform -> scalar loads (lgkmcnt), leaving vmcnt for x only.
template <int SEGS_T, int LOG2SEGS>
__global__ __launch_bounds__(64, 4) void lora_h_kernel(const float* __restrict__ x,
                                                       const float* __restrict__ bpack,
                                                       float* __restrict__ hpart) {
  constexpr int SEGD_T = D / SEGS_T;
  int w = blockIdx.x;
  int seg = w & (SEGS_T - 1);
  int rowblk = w >> LOG2SEGS;         // 0..511
  int b0 = rowblk >> 6;               // 64 rowblks per batch — wave-uniform SGPR
  int row = rowblk * 64 + threadIdx.x;
  const float* xr = x + (size_t)row * D + seg * SEGD_T;
  const float* bp = bpack + ((size_t)b0 * D + (size_t)seg * SEGD_T) * T;  // uniform

  float acc[T];
#pragma unroll
  for (int t = 0; t < T; ++t) acc[t] = 0.f;

#pragma unroll 8
  for (int d4 = 0; d4 < SEGD_T; d4 += 4) {
    float4 xv = *reinterpret_cast<const float4*>(xr + d4);
    const float4* b4 = reinterpret_cast<const float4*>(bp + (size_t)d4 * T);
#pragma unroll
    for (int dd = 0; dd < 4; ++dd) {
      float xs = (&xv.x)[dd];
#pragma unroll
      for (int tq = 0; tq < 4; ++tq) {
        float4 bv = b4[dd * 4 + tq];             // uniform -> s_load
        acc[tq * 4 + 0] = fmaf(xs, bv.x, acc[tq * 4 + 0]);
        acc[tq * 4 + 1] = fmaf(xs, bv.y, acc[tq * 4 + 1]);
        acc[tq * 4 + 2] = fmaf(xs, bv.z, acc[tq * 4 + 2]);
        acc[tq * 4 + 3] = fmaf(xs, bv.w, acc[tq * 4 + 3]);
      }
    }
  }

  float4* hp = reinterpret_cast<float4*>(hpart + ((size_t)seg * NROWS + row) * T);
#pragma unroll
  for (int q = 0; q < 4; ++q)
    hp[q] = make_float4(acc[q * 4 + 0], acc[q * 4 + 1], acc[q * 4 + 2], acc[q * 4 + 3]);
}

// Each thread owns 4 contiguous output columns (float4); A_cat slice scaled by
// 0.25 lives in 64 VGPRs for a 64-row tile. H reads are block-uniform -> s_load.
template <int SEGS_T>
__global__ __launch_bounds__(256) void lora_out_kernel(const float* __restrict__ hpart,
                                                       const float* __restrict__ aa,
                                                       float* __restrict__ out) {
  int blk = blockIdx.x;               // 0..1023
  int chunk = blk & 1;                // d half
  int rt = blk >> 1;                  // 0..511 row tiles of 64
  int row0 = rt * 64;
  int b0 = row0 >> 12;
  int d = chunk * (D / 2) + threadIdx.x * 4;

  float4 a[T];
#pragma unroll
  for (int t = 0; t < T; ++t) {
    // A_cat row t for batch b0 is adapter_a row (16*b0 + t) of the [N*R][D] view.
    float4 v = *reinterpret_cast<const float4*>(aa + (size_t)(16 * b0 + t) * D + d);
    a[t] = make_float4(v.x * 0.25f, v.y * 0.25f, v.z * 0.25f, v.w * 0.25f);
  }

  for (int r0 = 0; r0 < 64; ++r0) {
    int row = row0 + r0;
    float h[T];
#pragma unroll
    for (int t = 0; t < T; ++t) h[t] = hpart[(size_t)row * T + t];
#pragma unroll
    for (int s = 1; s < SEGS_T; ++s)
#pragma unroll
      for (int t = 0; t < T; ++t) h[t] += hpart[((size_t)s * NROWS + row) * T + t];

    float4 acc = make_float4(0.f, 0.f, 0.f, 0.f);
#pragma unroll
    for (int t = 0; t < T; ++t) {
      acc.x = fmaf(h[t], a[t].x, acc.x);
      acc.y = fmaf(h[t], a[t].y, acc.y);
      acc.z = fmaf(h[t], a[t].z, acc.z);
      acc.w = fmaf(h[t], a[t].w, acc.w);
    }
    *reinterpret_cast<float4*>(out + (size_t)row * D + d) =
        make_float4(fmaxf(acc.x, 0.f), fmaxf(acc.y, 0.f),
                    fmaxf(acc.z, 0.f), fmaxf(acc.w, 0.f));
  }
}

}  // namespace

extern "C" void kernel_launch(void* const* d_in, const int* in_sizes, int n_in,
                              void* d_out, int out_size, void* d_ws, size_t ws_size,
                              hipStream_t stream) {
  const float* x  = (const float*)d_in[0];   // [8,4096,2048]
  const float* ab = (const float*)d_in[1];   // [32,2048,4]
  const float* aa = (const float*)d_in[2];   // [32,4,2048]
  float* out = (float*)d_out;                // [8,4096,2048]

  float* bpack = (float*)d_ws;                          // B*D*T floats (2 MB)
  float* hpart = bpack + (size_t)B * D * T;             // SEGS*NROWS*T floats

  pack_b_kernel<<<(B * D * T + 255) / 256, 256, 0, stream>>>(ab, bpack);

  size_t need8 = ((size_t)B * D * T + (size_t)8 * NROWS * T) * sizeof(float);
  if (ws_size >= need8) {
    lora_h_kernel<8, 3><<<512 * 8, 64, 0, stream>>>(x, bpack, hpart);
    lora_out_kernel<8><<<1024, 256, 0, stream>>>(hpart, aa, out);
  } else {
    lora_h_kernel<2, 1><<<512 * 2, 64, 0, stream>>>(x, bpack, hpart);
    lora_out_kernel<2><<<1024, 256, 0, stream>>>(hpart, aa, out);
  }
}